// Round 9
// baseline (398.159 us; speedup 1.0000x reference)
//
#include <hip/hip_runtime.h>
#include <hip/hip_fp16.h>

typedef unsigned short ushort_t;
typedef unsigned int uint_t;
typedef __attribute__((ext_vector_type(8))) _Float16 half8;
typedef __attribute__((ext_vector_type(4))) float f32x4;

#define NN 50000
#define NE 800000
#define NGR 256
#define MAXDEG 64   // max observed degree ~45 (+1 self-loop); Poisson(16) tail ~1e-18

// async global->LDS, 16B per lane; LDS dest = wave-uniform base + lane*16
typedef __attribute__((address_space(3))) unsigned int as3_u32;
typedef const __attribute__((address_space(1))) unsigned int as1_u32c;
__device__ __forceinline__ void gld16(const ushort_t* g, void* lds_base) {
    __builtin_amdgcn_global_load_lds((as1_u32c*)g, (as3_u32*)lds_base, 16, 0, 0);
}

// ---- fused prep: x cast -> fp16, weights -> transposed fp16, ELL self-loop init ----
// colv is ushort (src < 50000 < 2^16): ELL table 6.4 MB, per-XCD slice 800 KB.
__global__ void k_prep(const float* __restrict__ x0, __half* __restrict__ xf,
                       const float* __restrict__ W0, const float* __restrict__ W1,
                       const float* __restrict__ W2, __half* __restrict__ th,
                       ushort_t* __restrict__ colv, int* __restrict__ deg) {
    int i = blockIdx.x * 256 + threadIdx.x;
    if (i < 1600000) {
        float4 v = ((const float4*)x0)[i];
        __half2 a = __floats2half2_rn(v.x, v.y);
        __half2 b = __floats2half2_rn(v.z, v.w);
        *(__half2*)(xf + i * 4) = a;
        *(__half2*)(xf + i * 4 + 2) = b;
    } else if (i < 1600000 + 114688) {
        int w = i - 1600000;
        const float* W; int K, NC, idx, base;
        if (w < 32768)      { W = W0; K = 128; NC = 256; idx = w;         base = 0; }
        else if (w < 98304) { W = W1; K = 256; NC = 256; idx = w - 32768; base = 32768; }
        else                { W = W2; K = 256; NC = 64;  idx = w - 98304; base = 98304; }
        int k = idx / NC, n = idx % NC;
        th[base + n * K + k] = __float2half(W[idx]);
    } else if (i < 1600000 + 114688 + NN) {
        int n = i - 1714688;
        colv[n << 6] = (ushort_t)n;   // self-loop at slot 0
        deg[n] = 1;
    }
}

// ---- standalone XCD-partitioned ELL fill (lean: no LDS, low VGPR) ----
// 4096-edge chunk/block x 8 XCD ranges. 16 edges/thread, 8 coalesced
// int4 loads issued up front, then 16 independent atomic chains.
// colv scatter is 2-B (ushort): half the lines of the int version, and
// the per-XCD colv slice (800 KB) stays L2-resident under the edge stream.
__global__ __launch_bounds__(256)
void k_fill(const int* __restrict__ esrc, const int* __restrict__ edst,
            int* __restrict__ deg, ushort_t* __restrict__ colv) {
    int r = blockIdx.x & 7;          // XCD heuristic (round-robin dispatch)
    int c = blockIdx.x >> 3;         // 4096-edge chunk
    int base = c * 4096 + (int)threadIdx.x * 4;
    int4 dv[4], sv[4];
    #pragma unroll
    for (int u = 0; u < 4; ++u) {
        int b = base + u * 1024;
        bool ok = b < NE;            // NE%4==0, b%4==0 -> b+3 < NE
        int bb = ok ? b : 0;
        dv[u] = *(const int4*)(edst + bb);
        sv[u] = *(const int4*)(esrc + bb);
        if (!ok) { dv[u].x = -1; dv[u].y = -1; dv[u].z = -1; dv[u].w = -1; }
    }
    const int lo = r * 6250;
    #pragma unroll
    for (int u = 0; u < 4; ++u) {
        const int* dp = (const int*)&dv[u];
        const int* sp = (const int*)&sv[u];
        #pragma unroll
        for (int j = 0; j < 4; ++j) {
            int d = dp[j];
            if ((unsigned)(d - lo) < 6250u) {
                int pos = atomicAdd(&deg[d], 1);
                if (pos < MAXDEG) colv[(d << 6) + pos] = (ushort_t)sp[j];
            }
        }
    }
}

// ------- GEMM body (fp16 single-term) + fused attention-logit epilogue -------
template<int KD, int BN>
__device__ __forceinline__ void gemm_body(int bx, int by,
    const __half* __restrict__ Ax, const __half* __restrict__ Bth,
    __half* __restrict__ Hout, const float* __restrict__ a_s,
    const float* __restrict__ a_d, float* __restrict__ als,
    float* __restrict__ ald, int H, int M, int NC) {
    constexpr int BM = 128, BK = 32;
    __shared__ ushort_t sA[BM * BK];
    __shared__ ushort_t sB[BN * BK];
    const int tid = threadIdx.x;
    const int m0 = bx * BM;
    const int n0 = by * BN;
    const int wv = tid >> 6, ln = tid & 63;
    const int lrow = ln & 15, lq = ln >> 4;
    constexpr int RT = (BN == 128) ? 4 : 2;
    int wm, wn;
    if constexpr (BN == 128) { wm = (wv >> 1) * 64; wn = (wv & 1) * 64; }
    else                     { wm = wv * 32;        wn = 0; }
    const int roff = ln >> 2;
    const int coff = (ln & 3) * 8;

    f32x4 acc[RT][4] = {};

    for (int k0 = 0; k0 < KD; k0 += BK) {
        #pragma unroll
        for (int ch = 0; ch < 2; ++ch) {
            int rb = wv * 32 + ch * 16;
            size_t ga = (size_t)(m0 + rb + roff) * KD + k0 + coff;
            gld16((const ushort_t*)Ax + ga, &sA[rb * BK]);
        }
        if constexpr (BN == 128) {
            #pragma unroll
            for (int ch = 0; ch < 2; ++ch) {
                int rb = wv * 32 + ch * 16;
                size_t gb = (size_t)(n0 + rb + roff) * KD + k0 + coff;
                gld16((const ushort_t*)Bth + gb, &sB[rb * BK]);
            }
        } else {
            int rb = wv * 16;
            size_t gb = (size_t)(n0 + rb + roff) * KD + k0 + coff;
            gld16((const ushort_t*)Bth + gb, &sB[rb * BK]);
        }
        __syncthreads();
        half8 af[RT], bf[4];
        #pragma unroll
        for (int r = 0; r < RT; ++r)
            af[r] = *(const half8*)&sA[(wm + r * 16 + lrow) * BK + lq * 8];
        #pragma unroll
        for (int c = 0; c < 4; ++c)
            bf[c] = *(const half8*)&sB[(wn + c * 16 + lrow) * BK + lq * 8];
        #pragma unroll
        for (int r = 0; r < RT; ++r)
            #pragma unroll
            for (int c = 0; c < 4; ++c)
                acc[r][c] = __builtin_amdgcn_mfma_f32_16x16x32_f16(af[r], bf[c], acc[r][c], 0, 0, 0);
        __syncthreads();
    }
    // H-store (C/D layout: col=lane&15, row=(lane>>4)*4+reg)
    #pragma unroll
    for (int r = 0; r < RT; ++r) {
        #pragma unroll
        for (int c = 0; c < 4; ++c) {
            int colg = n0 + wn + c * 16 + lrow;
            #pragma unroll
            for (int j = 0; j < 4; ++j) {
                int row = m0 + wm + r * 16 + lq * 4 + j;
                if (row < M) Hout[(size_t)row * NC + colg] = __float2half(acc[r][c][j]);
            }
        }
    }
    // fused attention logits: this wave's 64 cols lie in exactly one head
    int hh = (n0 + wn) >> 6;
    float asv[4], adv[4];
    #pragma unroll
    for (int c = 0; c < 4; ++c) {
        int cg = (n0 + wn + c * 16 + lrow) & 63;
        asv[c] = a_s[hh * 64 + cg];
        adv[c] = a_d[hh * 64 + cg];
    }
    #pragma unroll
    for (int r = 0; r < RT; ++r) {
        #pragma unroll
        for (int j = 0; j < 4; ++j) {
            float ts = 0.f, td = 0.f;
            #pragma unroll
            for (int c = 0; c < 4; ++c) {
                float v = acc[r][c][j];
                ts += v * asv[c];
                td += v * adv[c];
            }
            #pragma unroll
            for (int m = 1; m < 16; m <<= 1) {
                ts += __shfl_xor(ts, m);
                td += __shfl_xor(td, m);
            }
            int row = m0 + wm + r * 16 + lq * 4 + j;
            if (lrow == 0 && row < M) {
                als[row * H + hh] = ts;
                ald[row * H + hh] = td;
            }
        }
    }
}

template<int KD, int BN>
__global__ __launch_bounds__(256)
void k_mgemm(const __half* __restrict__ Ax, const __half* __restrict__ Bth,
             __half* __restrict__ Hout,
             const float* __restrict__ a_s, const float* __restrict__ a_d,
             float* __restrict__ als, float* __restrict__ ald,
             int H, int M, int NC) {
    gemm_body<KD, BN>(blockIdx.x, blockIdx.y, Ax, Bth, Hout, a_s, a_d, als, ald, H, M, NC);
}

// ---- CHANNEL-SPLIT fused softmax + aggregation + bias + BN + ELU (H=4) ----
__global__ __launch_bounds__(256)
void k_fagg4s(const __half* __restrict__ h, const float* __restrict__ als,
              const float* __restrict__ ald, const int* __restrict__ deg,
              const ushort_t* __restrict__ colv,
              const float* __restrict__ bias, const float* __restrict__ gam,
              const float* __restrict__ bet, const float* __restrict__ mu,
              const float* __restrict__ var,
              __half* __restrict__ xo, int M) {
    __shared__ uint_t wraw[4][64];     // uint per edge (2 fp16: this half's heads), 1KB
    int wv = threadIdx.x >> 6;
    int half = blockIdx.x & 1;
    int node = (blockIdx.x >> 1) * 4 + wv;
    if (node >= M) return;
    int l = threadIdx.x & 63;
    int dg = deg[node];                // [1,64]
    int rs = node << 6;

    // ---- phase A: logits -> e -> LDS weights + per-head denominator ----
    float2 ad = *(const float2*)(ald + (size_t)node * 4 + half * 2);
    bool vld = l < dg;
    int s = (int)colv[vld ? rs + l : rs];   // slot 0 (self-loop) always valid
    int cv = s;
    float2 av = *(const float2*)((const char*)als + ((size_t)(uint_t)s << 4) + half * 8);
    float e0 = av.x + ad.x; e0 = e0 > 0.f ? e0 : 0.2f * e0; e0 = vld ? __expf(e0) : 0.f;
    float e1 = av.y + ad.y; e1 = e1 > 0.f ? e1 : 0.2f * e1; e1 = vld ? __expf(e1) : 0.f;
    float d0 = e0, d1 = e1;
    __half2 p = __floats2half2_rn(e0, e1);
    wraw[wv][l] = *(uint_t*)&p;
    #pragma unroll
    for (int off = 1; off < 64; off <<= 1) {
        d0 += __shfl_xor(d0, off); d1 += __shfl_xor(d1, off);
    }

    // ---- phase B: weighted half-row gather (24-edge batches, LDS weights) ----
    float a0 = 0.f, a1 = 0.f;
    const uint_t shB = (uint_t)((l & 32) >> 1);        // head-in-half select: 0/16
    const uint_t loffB = (uint_t)(half * 256 + l * 4); // byte offset in row
    int nrem = dg;
    #pragma unroll
    for (int grp = 0; grp < 3; ++grp) {
        int g0 = grp * 24;
        if (g0 < nrem) {
            uint_t hu[3][8];
            #pragma unroll
            for (int bb = 0; bb < 3; ++bb) {
                if (g0 + bb * 8 < nrem) {
                    #pragma unroll
                    for (int u = 0; u < 8; ++u) {
                        int sv = __builtin_amdgcn_readlane(cv, g0 + bb * 8 + u);
                        const char* hp = (const char*)h + ((size_t)(uint_t)sv << 9);
                        hu[bb][u] = *(const uint_t*)(hp + loffB);
                    }
                }
            }
            #pragma unroll
            for (int bb = 0; bb < 3; ++bb) {
                if (g0 + bb * 8 < nrem) {
                    #pragma unroll
                    for (int u = 0; u < 8; ++u) {
                        int j = g0 + bb * 8 + u;           // static
                        uint_t w = wraw[wv][j];            // ds broadcast
                        uint_t afv = w >> shB;
                        asm("v_fma_mix_f32 %0, %1, %2, %0 op_sel:[0,0,0] op_sel_hi:[1,1,0]"
                            : "+v"(a0) : "v"(afv), "v"(hu[bb][u]));
                        asm("v_fma_mix_f32 %0, %1, %2, %0 op_sel:[0,1,0] op_sel_hi:[1,1,0]"
                            : "+v"(a1) : "v"(afv), "v"(hu[bb][u]));
                    }
                }
            }
        }
    }

    // ---- epilogue: 1/den + bias + BN + ELU (2 channels/lane) ----
    float den = (l & 32) ? d1 : d0;
    float inv = 1.f / (den + 1e-16f);
    int chg = half * 128 + l * 2;
    float2 bi = *(const float2*)(bias + chg);
    float2 ga = *(const float2*)(gam + chg);
    float2 be = *(const float2*)(bet + chg);
    float2 m2 = *(const float2*)(mu + chg);
    float2 v2 = *(const float2*)(var + chg);
    float o0 = a0 * inv + bi.x;
    float o1 = a1 * inv + bi.y;
    float bn0 = (o0 - m2.x) * rsqrtf(v2.x + 1e-5f) * ga.x + be.x;
    float bn1 = (o1 - m2.y) * rsqrtf(v2.y + 1e-5f) * ga.y + be.y;
    float f0 = bn0 > 0.f ? bn0 : (__expf(bn0) - 1.f);
    float f1 = bn1 > 0.f ? bn1 : (__expf(bn1) - 1.f);
    __half2 pk = __floats2half2_rn(f0, f1);
    *(uint_t*)&xo[(size_t)node * 256 + chg] = *(uint_t*)&pk;
}

// ---- FUSED softmax + aggregation + bias + BN + ELU (H=1, ELL) ----
__global__ __launch_bounds__(256)
void k_fagg1(const __half* __restrict__ h, const float* __restrict__ als,
             const float* __restrict__ ald, const int* __restrict__ deg,
             const ushort_t* __restrict__ colv,
             const float* __restrict__ bias, const float* __restrict__ gam,
             const float* __restrict__ bet, const float* __restrict__ mu,
             const float* __restrict__ var,
             float* __restrict__ xf, int M) {
    __shared__ uint_t wraw[4][64];
    int node = blockIdx.x * 4 + (threadIdx.x >> 6);
    if (node >= M) return;
    int wv = (threadIdx.x >> 6) & 3;
    int l = threadIdx.x & 63;
    int dg = deg[node];
    int rs = node << 6;

    float ad = ald[node];
    bool vld = l < dg;
    int s = (int)colv[vld ? rs + l : rs];
    int cv = s;
    float e = als[s] + ad; e = e > 0.f ? e : 0.2f * e; e = vld ? __expf(e) : 0.f;
    float d0 = e;
    wraw[wv][l] = __float_as_uint(e);
    #pragma unroll
    for (int off = 1; off < 64; off <<= 1) d0 += __shfl_xor(d0, off);

    float a0 = 0.f;
    int nrem = dg;
    #pragma unroll
    for (int grp = 0; grp < 3; ++grp) {
        int g0 = grp * 24;
        if (g0 < nrem) {
            uint_t hu[3][8];
            #pragma unroll
            for (int bb = 0; bb < 3; ++bb) {
                if (g0 + bb * 8 < nrem) {
                    #pragma unroll
                    for (int u = 0; u < 8; ++u) {
                        int sv = __builtin_amdgcn_readlane(cv, g0 + bb * 8 + u);
                        const ushort_t* hp = (const ushort_t*)h + ((size_t)(uint_t)sv << 6);
                        hu[bb][u] = (uint_t)hp[l];
                    }
                }
            }
            #pragma unroll
            for (int bb = 0; bb < 3; ++bb) {
                if (g0 + bb * 8 < nrem) {
                    #pragma unroll
                    for (int u = 0; u < 8; ++u) {
                        int j = g0 + bb * 8 + u;
                        uint_t wfv = wraw[wv][j];
                        asm("v_fma_mix_f32 %0, %1, %2, %0 op_sel:[0,0,0] op_sel_hi:[0,1,0]"
                            : "+v"(a0) : "v"(wfv), "v"(hu[bb][u]));
                    }
                }
            }
        }
    }

    float inv = 1.f / (d0 + 1e-16f);
    float o = a0 * inv + bias[l];
    float bn = (o - mu[l]) * rsqrtf(var[l] + 1e-5f) * gam[l] + bet[l];
    float fo = bn > 0.f ? bn : (__expf(bn) - 1.f);
    xf[(size_t)node * 64 + l] = fo;
}

// ---- fused pooling + MLP: 512 threads = 8 node-subsets x 64 dims, LDS reduce ----
__global__ __launch_bounds__(512)
void k_poolfc(const float* __restrict__ x, const int* __restrict__ batch,
              const float* __restrict__ fc1w, const float* __restrict__ fc1b,
              const float* __restrict__ fc2w, const float* __restrict__ fc2b,
              const float* __restrict__ fc3w, const float* __restrict__ fc3b,
              float* __restrict__ out, int M) {
    __shared__ float ssum[8][64];
    __shared__ float smax[8][64];
    __shared__ float hb[192];
    __shared__ float h1[64];
    __shared__ float h2[32];
    int g = blockIdx.x, t = threadIdx.x;
    int d = t & 63, sub = t >> 6;    // 8 subsets
    int lo = 0, hi = M;
    while (lo < hi) { int mid = (lo + hi) >> 1; if (batch[mid] < g) lo = mid + 1; else hi = mid; }
    int s = lo;
    lo = 0; hi = M;
    while (lo < hi) { int mid = (lo + hi) >> 1; if (batch[mid] < g + 1) lo = mid + 1; else hi = mid; }
    int e = lo;
    float sum = 0.f, mx = -3.0e38f;
    for (int n = s + sub; n < e; n += 8) {
        float v = x[(size_t)n * 64 + d];
        sum += v; mx = fmaxf(mx, v);
    }
    ssum[sub][d] = sum; smax[sub][d] = mx;
    __syncthreads();
    if (t < 64) {
        float sm = 0.f, m2 = -3.0e38f;
        #pragma unroll
        for (int k = 0; k < 8; ++k) { sm += ssum[k][t]; m2 = fmaxf(m2, smax[k][t]); }
        int cnt = e - s;
        hb[t] = sm / (float)(cnt > 1 ? cnt : 1);
        hb[64 + t] = (cnt == 0) ? 0.f : m2;
        hb[128 + t] = sm;
    }
    __syncthreads();
    if (t < 64) {
        float s1 = fc1b[t];
        for (int k = 0; k < 192; ++k) s1 += hb[k] * fc1w[k * 64 + t];
        h1[t] = fmaxf(s1, 0.f);
    }
    __syncthreads();
    if (t < 32) {
        float s2 = fc2b[t];
        for (int k = 0; k < 64; ++k) s2 += h1[k] * fc2w[k * 32 + t];
        h2[t] = fmaxf(s2, 0.f);
    }
    __syncthreads();
    if (t == 0) {
        float s3 = fc3b[0];
        for (int k = 0; k < 32; ++k) s3 += h2[k] * fc3w[k];
        out[g] = s3;
    }
}

extern "C" void kernel_launch(void* const* d_in, const int* in_sizes, int n_in,
                              void* d_out, int out_size, void* d_ws, size_t ws_size,
                              hipStream_t stream) {
    const float* x0     = (const float*)d_in[0];
    const int* ei       = (const int*)d_in[1];
    const int* batch    = (const int*)d_in[2];
    const float* W[3]   = {(const float*)d_in[3],  (const float*)d_in[11], (const float*)d_in[19]};
    const float* AS[3]  = {(const float*)d_in[4],  (const float*)d_in[12], (const float*)d_in[20]};
    const float* AD[3]  = {(const float*)d_in[5],  (const float*)d_in[13], (const float*)d_in[21]};
    const float* BI[3]  = {(const float*)d_in[6],  (const float*)d_in[14], (const float*)d_in[22]};
    const float* GA[3]  = {(const float*)d_in[7],  (const float*)d_in[15], (const float*)d_in[23]};
    const float* BE[3]  = {(const float*)d_in[8],  (const float*)d_in[16], (const float*)d_in[24]};
    const float* MU[3]  = {(const float*)d_in[9],  (const float*)d_in[17], (const float*)d_in[25]};
    const float* VA[3]  = {(const float*)d_in[10], (const float*)d_in[18], (const float*)d_in[26]};
    const float* fc1w = (const float*)d_in[27];
    const float* fc1b = (const float*)d_in[28];
    const float* fc2w = (const float*)d_in[29];
    const float* fc2b = (const float*)d_in[30];
    const float* fc3w = (const float*)d_in[31];
    const float* fc3b = (const float*)d_in[32];

    // ELL(ushort) workspace: top of use = 72,454,144 B (< 108,953,600 B proven safe).
    char* ws = (char*)d_ws;
    ushort_t* colv = (ushort_t*)(ws);                  // 6,400,000 B (50k x 64 ELL, u16)
    int*   deg    = (int*)  (ws + 6400000);            // 200,000 B
    float* als    = (float*)(ws + 6600192);            // 800,000 B
    float* ald    = (float*)(ws + 7400192);            // 800,000 B
    __half* wTh   = (__half*)(ws + 8200192);           // 229,376 B (3 layers packed)
    __half* h_buf = (__half*)(ws + 8429568);           // 25,600,000 B
    __half* xf16  = (__half*)(ws + 34029568);          // 25,624,576 B (50048 rows x 256)
    float* xpool  = (float*)(ws + 59654144);           // 12,800,000 B -> 72,454,144 B

    const int* esrc = ei;
    const int* edst = ei + NE;

    // prep: x cast + W split + ELL self-loop init (deg=1, slot 0 = self)
    k_prep<<<(1600000 + 114688 + NN + 255) / 256, 256, 0, stream>>>(x0, xf16, W[0], W[1], W[2],
                                                                    wTh, colv, deg);

    const int GB = (NN + 127) / 128; // 391
    const int FILLB = ((NE + 4095) / 4096) * 8; // 1568 (4096-edge chunks x 8 XCD ranges)
    int nwb = (NN + 3) / 4;          // 12500
    int nsb = nwb * 2;               // 25000 (channel-split: x2 halves)

    // ---- layer 0 (K=128, HC=256, H=4): fill and GEMM as SEPARATE kernels
    // (diagnostic split per R7 pre-commit; lean fill = no LDS, low VGPR)
    k_fill<<<FILLB, 256, 0, stream>>>(esrc, edst, deg, colv);
    k_mgemm<128, 128><<<dim3(GB, 2), 256, 0, stream>>>(xf16, wTh, h_buf,
                                                       AS[0], AD[0], als, ald, 4, NN, 256);
    k_fagg4s<<<nsb, 256, 0, stream>>>(h_buf, als, ald, deg, colv,
                                      BI[0], GA[0], BE[0], MU[0], VA[0], xf16, NN);
    // ---- layer 1 (K=256, HC=256, H=4)
    k_mgemm<256, 128><<<dim3(GB, 2), 256, 0, stream>>>(xf16, wTh + 32768, h_buf,
                                                       AS[1], AD[1], als, ald, 4, NN, 256);
    k_fagg4s<<<nsb, 256, 0, stream>>>(h_buf, als, ald, deg, colv,
                                      BI[1], GA[1], BE[1], MU[1], VA[1], xf16, NN);
    // ---- layer 2 (K=256, HC=64, H=1)
    k_mgemm<256, 64><<<dim3(GB, 1), 256, 0, stream>>>(xf16, wTh + 98304, h_buf,
                                                      AS[2], AD[2], als, ald, 1, NN, 64);
    k_fagg1<<<nwb, 256, 0, stream>>>(h_buf, als, ald, deg, colv,
                                     BI[2], GA[2], BE[2], MU[2], VA[2], xpool, NN);

    // fused readout + MLP (512 threads: 8 node-subsets x 64 dims)
    k_poolfc<<<NGR, 512, 0, stream>>>(xpool, batch, fc1w, fc1b, fc2w, fc2b, fc3w, fc3b,
                                      (float*)d_out, NN);
    (void)in_sizes; (void)n_in; (void)out_size; (void)ws_size;
}

// Round 10
// 388.274 us; speedup vs baseline: 1.0255x; 1.0255x over previous
//
#include <hip/hip_runtime.h>
#include <hip/hip_fp16.h>

typedef unsigned short ushort_t;
typedef unsigned int uint_t;
typedef __attribute__((ext_vector_type(8))) _Float16 half8;
typedef __attribute__((ext_vector_type(4))) float f32x4;

#define NN 50000
#define NE 800000
#define NGR 256
#define MAXDEG 64   // max observed degree ~45 (+1 self-loop); Poisson(16) tail ~1e-18

// async global->LDS, 16B per lane; LDS dest = wave-uniform base + lane*16
typedef __attribute__((address_space(3))) unsigned int as3_u32;
typedef const __attribute__((address_space(1))) unsigned int as1_u32c;
__device__ __forceinline__ void gld16(const ushort_t* g, void* lds_base) {
    __builtin_amdgcn_global_load_lds((as1_u32c*)g, (as3_u32*)lds_base, 16, 0, 0);
}

// ---- FUSED prep + ELL fill ----
// blocks [0,FILLB): XCD-partitioned fill (the long pole, starts first).
//   deg pre-zeroed by memset; edge slots are 1+pos (slot 0 = self-loop),
//   so fill has NO dependency on the prep blocks (disjoint colv bytes).
// blocks [FILLB,..): prep = x cast -> fp16, W -> transposed fp16,
//   self-loop plant (colv slot 0 only).
// Mechanism (R7/R8 A/B): fill waves are atomic-latency-bound; prep's
// streaming cast/transpose co-schedules under them ~for free.
__global__ __launch_bounds__(256)
void k_pf(const float* __restrict__ x0, __half* __restrict__ xf,
          const float* __restrict__ W0, const float* __restrict__ W1,
          const float* __restrict__ W2, __half* __restrict__ th,
          const int* __restrict__ esrc, const int* __restrict__ edst,
          int* __restrict__ deg, ushort_t* __restrict__ colv) {
    constexpr int FILLB = ((NE + 4095) / 4096) * 8;   // 1568
    if (blockIdx.x < FILLB) {
        int r = blockIdx.x & 7;          // XCD heuristic (round-robin dispatch)
        int c = blockIdx.x >> 3;         // 4096-edge chunk
        int base = c * 4096 + (int)threadIdx.x * 4;
        int4 dv[4], sv[4];
        #pragma unroll
        for (int u = 0; u < 4; ++u) {
            int b = base + u * 1024;
            bool ok = b < NE;            // NE%4==0, b%4==0 -> b+3 < NE
            int bb = ok ? b : 0;
            dv[u] = *(const int4*)(edst + bb);
            sv[u] = *(const int4*)(esrc + bb);
            if (!ok) { dv[u].x = -1; dv[u].y = -1; dv[u].z = -1; dv[u].w = -1; }
        }
        const int lo = r * 6250;
        #pragma unroll
        for (int u = 0; u < 4; ++u) {
            const int* dp = (const int*)&dv[u];
            const int* sp = (const int*)&sv[u];
            #pragma unroll
            for (int j = 0; j < 4; ++j) {
                int d = dp[j];
                if ((unsigned)(d - lo) < 6250u) {
                    int pos = atomicAdd(&deg[d], 1);           // 0-based edge slot
                    if (pos < MAXDEG - 1) colv[(d << 6) + 1 + pos] = (ushort_t)sp[j];
                }
            }
        }
    } else {
        int i = (blockIdx.x - FILLB) * 256 + threadIdx.x;
        if (i < 1600000) {
            float4 v = ((const float4*)x0)[i];
            __half2 a = __floats2half2_rn(v.x, v.y);
            __half2 b = __floats2half2_rn(v.z, v.w);
            *(__half2*)(xf + i * 4) = a;
            *(__half2*)(xf + i * 4 + 2) = b;
        } else if (i < 1600000 + 114688) {
            int w = i - 1600000;
            const float* W; int K, NC, idx, base;
            if (w < 32768)      { W = W0; K = 128; NC = 256; idx = w;         base = 0; }
            else if (w < 98304) { W = W1; K = 256; NC = 256; idx = w - 32768; base = 32768; }
            else                { W = W2; K = 256; NC = 64;  idx = w - 98304; base = 98304; }
            int k = idx / NC, n = idx % NC;
            th[base + n * K + k] = __float2half(W[idx]);
        } else if (i < 1600000 + 114688 + NN) {
            int n = i - 1714688;
            colv[n << 6] = (ushort_t)n;   // self-loop at slot 0 (fill never writes slot 0)
        }
    }
}

// ------- GEMM body (fp16 single-term) + fused attention-logit epilogue -------
template<int KD, int BN>
__device__ __forceinline__ void gemm_body(int bx, int by,
    const __half* __restrict__ Ax, const __half* __restrict__ Bth,
    __half* __restrict__ Hout, const float* __restrict__ a_s,
    const float* __restrict__ a_d, float* __restrict__ als,
    float* __restrict__ ald, int H, int M, int NC) {
    constexpr int BM = 128, BK = 32;
    __shared__ ushort_t sA[BM * BK];
    __shared__ ushort_t sB[BN * BK];
    const int tid = threadIdx.x;
    const int m0 = bx * BM;
    const int n0 = by * BN;
    const int wv = tid >> 6, ln = tid & 63;
    const int lrow = ln & 15, lq = ln >> 4;
    constexpr int RT = (BN == 128) ? 4 : 2;
    int wm, wn;
    if constexpr (BN == 128) { wm = (wv >> 1) * 64; wn = (wv & 1) * 64; }
    else                     { wm = wv * 32;        wn = 0; }
    const int roff = ln >> 2;
    const int coff = (ln & 3) * 8;

    f32x4 acc[RT][4] = {};

    for (int k0 = 0; k0 < KD; k0 += BK) {
        #pragma unroll
        for (int ch = 0; ch < 2; ++ch) {
            int rb = wv * 32 + ch * 16;
            size_t ga = (size_t)(m0 + rb + roff) * KD + k0 + coff;
            gld16((const ushort_t*)Ax + ga, &sA[rb * BK]);
        }
        if constexpr (BN == 128) {
            #pragma unroll
            for (int ch = 0; ch < 2; ++ch) {
                int rb = wv * 32 + ch * 16;
                size_t gb = (size_t)(n0 + rb + roff) * KD + k0 + coff;
                gld16((const ushort_t*)Bth + gb, &sB[rb * BK]);
            }
        } else {
            int rb = wv * 16;
            size_t gb = (size_t)(n0 + rb + roff) * KD + k0 + coff;
            gld16((const ushort_t*)Bth + gb, &sB[rb * BK]);
        }
        __syncthreads();
        half8 af[RT], bf[4];
        #pragma unroll
        for (int r = 0; r < RT; ++r)
            af[r] = *(const half8*)&sA[(wm + r * 16 + lrow) * BK + lq * 8];
        #pragma unroll
        for (int c = 0; c < 4; ++c)
            bf[c] = *(const half8*)&sB[(wn + c * 16 + lrow) * BK + lq * 8];
        #pragma unroll
        for (int r = 0; r < RT; ++r)
            #pragma unroll
            for (int c = 0; c < 4; ++c)
                acc[r][c] = __builtin_amdgcn_mfma_f32_16x16x32_f16(af[r], bf[c], acc[r][c], 0, 0, 0);
        __syncthreads();
    }
    // H-store (C/D layout: col=lane&15, row=(lane>>4)*4+reg)
    #pragma unroll
    for (int r = 0; r < RT; ++r) {
        #pragma unroll
        for (int c = 0; c < 4; ++c) {
            int colg = n0 + wn + c * 16 + lrow;
            #pragma unroll
            for (int j = 0; j < 4; ++j) {
                int row = m0 + wm + r * 16 + lq * 4 + j;
                if (row < M) Hout[(size_t)row * NC + colg] = __float2half(acc[r][c][j]);
            }
        }
    }
    // fused attention logits: this wave's 64 cols lie in exactly one head
    int hh = (n0 + wn) >> 6;
    float asv[4], adv[4];
    #pragma unroll
    for (int c = 0; c < 4; ++c) {
        int cg = (n0 + wn + c * 16 + lrow) & 63;
        asv[c] = a_s[hh * 64 + cg];
        adv[c] = a_d[hh * 64 + cg];
    }
    #pragma unroll
    for (int r = 0; r < RT; ++r) {
        #pragma unroll
        for (int j = 0; j < 4; ++j) {
            float ts = 0.f, td = 0.f;
            #pragma unroll
            for (int c = 0; c < 4; ++c) {
                float v = acc[r][c][j];
                ts += v * asv[c];
                td += v * adv[c];
            }
            #pragma unroll
            for (int m = 1; m < 16; m <<= 1) {
                ts += __shfl_xor(ts, m);
                td += __shfl_xor(td, m);
            }
            int row = m0 + wm + r * 16 + lq * 4 + j;
            if (lrow == 0 && row < M) {
                als[row * H + hh] = ts;
                ald[row * H + hh] = td;
            }
        }
    }
}

template<int KD, int BN>
__global__ __launch_bounds__(256)
void k_mgemm(const __half* __restrict__ Ax, const __half* __restrict__ Bth,
             __half* __restrict__ Hout,
             const float* __restrict__ a_s, const float* __restrict__ a_d,
             float* __restrict__ als, float* __restrict__ ald,
             int H, int M, int NC) {
    gemm_body<KD, BN>(blockIdx.x, blockIdx.y, Ax, Bth, Hout, a_s, a_d, als, ald, H, M, NC);
}

// ---- CHANNEL-SPLIT fused softmax + aggregation + bias + BN + ELU (H=4) ----
// deg[] now counts EDGES only (0-based); total slots = deg+1 (slot 0 = self).
__global__ __launch_bounds__(256)
void k_fagg4s(const __half* __restrict__ h, const float* __restrict__ als,
              const float* __restrict__ ald, const int* __restrict__ deg,
              const ushort_t* __restrict__ colv,
              const float* __restrict__ bias, const float* __restrict__ gam,
              const float* __restrict__ bet, const float* __restrict__ mu,
              const float* __restrict__ var,
              __half* __restrict__ xo, int M) {
    __shared__ uint_t wraw[4][64];     // uint per edge (2 fp16: this half's heads), 1KB
    int wv = threadIdx.x >> 6;
    int half = blockIdx.x & 1;
    int node = (blockIdx.x >> 1) * 4 + wv;
    if (node >= M) return;
    int l = threadIdx.x & 63;
    int dg = deg[node] + 1;            // [1,64] total slots incl. self-loop
    if (dg > MAXDEG) dg = MAXDEG;
    int rs = node << 6;

    // ---- phase A: logits -> e -> LDS weights + per-head denominator ----
    float2 ad = *(const float2*)(ald + (size_t)node * 4 + half * 2);
    bool vld = l < dg;
    int s = (int)colv[vld ? rs + l : rs];   // slot 0 (self-loop) always valid
    int cv = s;
    float2 av = *(const float2*)((const char*)als + ((size_t)(uint_t)s << 4) + half * 8);
    float e0 = av.x + ad.x; e0 = e0 > 0.f ? e0 : 0.2f * e0; e0 = vld ? __expf(e0) : 0.f;
    float e1 = av.y + ad.y; e1 = e1 > 0.f ? e1 : 0.2f * e1; e1 = vld ? __expf(e1) : 0.f;
    float d0 = e0, d1 = e1;
    __half2 p = __floats2half2_rn(e0, e1);
    wraw[wv][l] = *(uint_t*)&p;
    #pragma unroll
    for (int off = 1; off < 64; off <<= 1) {
        d0 += __shfl_xor(d0, off); d1 += __shfl_xor(d1, off);
    }

    // ---- phase B: weighted half-row gather (24-edge batches, LDS weights) ----
    float a0 = 0.f, a1 = 0.f;
    const uint_t shB = (uint_t)((l & 32) >> 1);        // head-in-half select: 0/16
    const uint_t loffB = (uint_t)(half * 256 + l * 4); // byte offset in row
    int nrem = dg;
    #pragma unroll
    for (int grp = 0; grp < 3; ++grp) {
        int g0 = grp * 24;
        if (g0 < nrem) {
            uint_t hu[3][8];
            #pragma unroll
            for (int bb = 0; bb < 3; ++bb) {
                if (g0 + bb * 8 < nrem) {
                    #pragma unroll
                    for (int u = 0; u < 8; ++u) {
                        int sv = __builtin_amdgcn_readlane(cv, g0 + bb * 8 + u);
                        const char* hp = (const char*)h + ((size_t)(uint_t)sv << 9);
                        hu[bb][u] = *(const uint_t*)(hp + loffB);
                    }
                }
            }
            #pragma unroll
            for (int bb = 0; bb < 3; ++bb) {
                if (g0 + bb * 8 < nrem) {
                    #pragma unroll
                    for (int u = 0; u < 8; ++u) {
                        int j = g0 + bb * 8 + u;           // static
                        uint_t w = wraw[wv][j];            // ds broadcast
                        uint_t afv = w >> shB;
                        asm("v_fma_mix_f32 %0, %1, %2, %0 op_sel:[0,0,0] op_sel_hi:[1,1,0]"
                            : "+v"(a0) : "v"(afv), "v"(hu[bb][u]));
                        asm("v_fma_mix_f32 %0, %1, %2, %0 op_sel:[0,1,0] op_sel_hi:[1,1,0]"
                            : "+v"(a1) : "v"(afv), "v"(hu[bb][u]));
                    }
                }
            }
        }
    }

    // ---- epilogue: 1/den + bias + BN + ELU (2 channels/lane) ----
    float den = (l & 32) ? d1 : d0;
    float inv = 1.f / (den + 1e-16f);
    int chg = half * 128 + l * 2;
    float2 bi = *(const float2*)(bias + chg);
    float2 ga = *(const float2*)(gam + chg);
    float2 be = *(const float2*)(bet + chg);
    float2 m2 = *(const float2*)(mu + chg);
    float2 v2 = *(const float2*)(var + chg);
    float o0 = a0 * inv + bi.x;
    float o1 = a1 * inv + bi.y;
    float bn0 = (o0 - m2.x) * rsqrtf(v2.x + 1e-5f) * ga.x + be.x;
    float bn1 = (o1 - m2.y) * rsqrtf(v2.y + 1e-5f) * ga.y + be.y;
    float f0 = bn0 > 0.f ? bn0 : (__expf(bn0) - 1.f);
    float f1 = bn1 > 0.f ? bn1 : (__expf(bn1) - 1.f);
    __half2 pk = __floats2half2_rn(f0, f1);
    *(uint_t*)&xo[(size_t)node * 256 + chg] = *(uint_t*)&pk;
}

// ---- FUSED softmax + aggregation + bias + BN + ELU (H=1, ELL) ----
__global__ __launch_bounds__(256)
void k_fagg1(const __half* __restrict__ h, const float* __restrict__ als,
             const float* __restrict__ ald, const int* __restrict__ deg,
             const ushort_t* __restrict__ colv,
             const float* __restrict__ bias, const float* __restrict__ gam,
             const float* __restrict__ bet, const float* __restrict__ mu,
             const float* __restrict__ var,
             float* __restrict__ xf, int M) {
    __shared__ uint_t wraw[4][64];
    int node = blockIdx.x * 4 + (threadIdx.x >> 6);
    if (node >= M) return;
    int wv = (threadIdx.x >> 6) & 3;
    int l = threadIdx.x & 63;
    int dg = deg[node] + 1;
    if (dg > MAXDEG) dg = MAXDEG;
    int rs = node << 6;

    float ad = ald[node];
    bool vld = l < dg;
    int s = (int)colv[vld ? rs + l : rs];
    int cv = s;
    float e = als[s] + ad; e = e > 0.f ? e : 0.2f * e; e = vld ? __expf(e) : 0.f;
    float d0 = e;
    wraw[wv][l] = __float_as_uint(e);
    #pragma unroll
    for (int off = 1; off < 64; off <<= 1) d0 += __shfl_xor(d0, off);

    float a0 = 0.f;
    int nrem = dg;
    #pragma unroll
    for (int grp = 0; grp < 3; ++grp) {
        int g0 = grp * 24;
        if (g0 < nrem) {
            uint_t hu[3][8];
            #pragma unroll
            for (int bb = 0; bb < 3; ++bb) {
                if (g0 + bb * 8 < nrem) {
                    #pragma unroll
                    for (int u = 0; u < 8; ++u) {
                        int sv = __builtin_amdgcn_readlane(cv, g0 + bb * 8 + u);
                        const ushort_t* hp = (const ushort_t*)h + ((size_t)(uint_t)sv << 6);
                        hu[bb][u] = (uint_t)hp[l];
                    }
                }
            }
            #pragma unroll
            for (int bb = 0; bb < 3; ++bb) {
                if (g0 + bb * 8 < nrem) {
                    #pragma unroll
                    for (int u = 0; u < 8; ++u) {
                        int j = g0 + bb * 8 + u;
                        uint_t wfv = wraw[wv][j];
                        asm("v_fma_mix_f32 %0, %1, %2, %0 op_sel:[0,0,0] op_sel_hi:[0,1,0]"
                            : "+v"(a0) : "v"(wfv), "v"(hu[bb][u]));
                    }
                }
            }
        }
    }

    float inv = 1.f / (d0 + 1e-16f);
    float o = a0 * inv + bias[l];
    float bn = (o - mu[l]) * rsqrtf(var[l] + 1e-5f) * gam[l] + bet[l];
    float fo = bn > 0.f ? bn : (__expf(bn) - 1.f);
    xf[(size_t)node * 64 + l] = fo;
}

// ---- fused pooling + MLP: 512 threads = 8 node-subsets x 64 dims, LDS reduce ----
__global__ __launch_bounds__(512)
void k_poolfc(const float* __restrict__ x, const int* __restrict__ batch,
              const float* __restrict__ fc1w, const float* __restrict__ fc1b,
              const float* __restrict__ fc2w, const float* __restrict__ fc2b,
              const float* __restrict__ fc3w, const float* __restrict__ fc3b,
              float* __restrict__ out, int M) {
    __shared__ float ssum[8][64];
    __shared__ float smax[8][64];
    __shared__ float hb[192];
    __shared__ float h1[64];
    __shared__ float h2[32];
    int g = blockIdx.x, t = threadIdx.x;
    int d = t & 63, sub = t >> 6;    // 8 subsets
    int lo = 0, hi = M;
    while (lo < hi) { int mid = (lo + hi) >> 1; if (batch[mid] < g) lo = mid + 1; else hi = mid; }
    int s = lo;
    lo = 0; hi = M;
    while (lo < hi) { int mid = (lo + hi) >> 1; if (batch[mid] < g + 1) lo = mid + 1; else hi = mid; }
    int e = lo;
    float sum = 0.f, mx = -3.0e38f;
    for (int n = s + sub; n < e; n += 8) {
        float v = x[(size_t)n * 64 + d];
        sum += v; mx = fmaxf(mx, v);
    }
    ssum[sub][d] = sum; smax[sub][d] = mx;
    __syncthreads();
    if (t < 64) {
        float sm = 0.f, m2 = -3.0e38f;
        #pragma unroll
        for (int k = 0; k < 8; ++k) { sm += ssum[k][t]; m2 = fmaxf(m2, smax[k][t]); }
        int cnt = e - s;
        hb[t] = sm / (float)(cnt > 1 ? cnt : 1);
        hb[64 + t] = (cnt == 0) ? 0.f : m2;
        hb[128 + t] = sm;
    }
    __syncthreads();
    if (t < 64) {
        float s1 = fc1b[t];
        for (int k = 0; k < 192; ++k) s1 += hb[k] * fc1w[k * 64 + t];
        h1[t] = fmaxf(s1, 0.f);
    }
    __syncthreads();
    if (t < 32) {
        float s2 = fc2b[t];
        for (int k = 0; k < 64; ++k) s2 += h1[k] * fc2w[k * 32 + t];
        h2[t] = fmaxf(s2, 0.f);
    }
    __syncthreads();
    if (t == 0) {
        float s3 = fc3b[0];
        for (int k = 0; k < 32; ++k) s3 += h2[k] * fc3w[k];
        out[g] = s3;
    }
}

extern "C" void kernel_launch(void* const* d_in, const int* in_sizes, int n_in,
                              void* d_out, int out_size, void* d_ws, size_t ws_size,
                              hipStream_t stream) {
    const float* x0     = (const float*)d_in[0];
    const int* ei       = (const int*)d_in[1];
    const int* batch    = (const int*)d_in[2];
    const float* W[3]   = {(const float*)d_in[3],  (const float*)d_in[11], (const float*)d_in[19]};
    const float* AS[3]  = {(const float*)d_in[4],  (const float*)d_in[12], (const float*)d_in[20]};
    const float* AD[3]  = {(const float*)d_in[5],  (const float*)d_in[13], (const float*)d_in[21]};
    const float* BI[3]  = {(const float*)d_in[6],  (const float*)d_in[14], (const float*)d_in[22]};
    const float* GA[3]  = {(const float*)d_in[7],  (const float*)d_in[15], (const float*)d_in[23]};
    const float* BE[3]  = {(const float*)d_in[8],  (const float*)d_in[16], (const float*)d_in[24]};
    const float* MU[3]  = {(const float*)d_in[9],  (const float*)d_in[17], (const float*)d_in[25]};
    const float* VA[3]  = {(const float*)d_in[10], (const float*)d_in[18], (const float*)d_in[26]};
    const float* fc1w = (const float*)d_in[27];
    const float* fc1b = (const float*)d_in[28];
    const float* fc2w = (const float*)d_in[29];
    const float* fc2b = (const float*)d_in[30];
    const float* fc3w = (const float*)d_in[31];
    const float* fc3b = (const float*)d_in[32];

    // ELL(ushort) workspace: top of use = 72,454,144 B (< 108,953,600 B proven safe).
    char* ws = (char*)d_ws;
    ushort_t* colv = (ushort_t*)(ws);                  // 6,400,000 B (50k x 64 ELL, u16)
    int*   deg    = (int*)  (ws + 6400000);            // 200,000 B
    float* als    = (float*)(ws + 6600192);            // 800,000 B
    float* ald    = (float*)(ws + 7400192);            // 800,000 B
    __half* wTh   = (__half*)(ws + 8200192);           // 229,376 B (3 layers packed)
    __half* h_buf = (__half*)(ws + 8429568);           // 25,600,000 B
    __half* xf16  = (__half*)(ws + 34029568);          // 25,624,576 B (50048 rows x 256)
    float* xpool  = (float*)(ws + 59654144);           // 12,800,000 B -> 72,454,144 B

    const int* esrc = ei;
    const int* edst = ei + NE;

    const int GB = (NN + 127) / 128; // 391
    const int FILLB = ((NE + 4095) / 4096) * 8; // 1568 (4096-edge chunks x 8 XCD ranges)
    const int PREPB = (1600000 + 114688 + NN + 255) / 256; // 6894
    int nwb = (NN + 3) / 4;          // 12500
    int nsb = nwb * 2;               // 25000 (channel-split: x2 halves)

    // deg = 0 (edge count; self-loop handled by slot-0 plant in k_pf prep blocks)
    hipMemsetAsync(deg, 0, NN * sizeof(int), stream);

    // ---- fused prep + fill (fill blocks first: long pole; prep overlaps)
    k_pf<<<FILLB + PREPB, 256, 0, stream>>>(x0, xf16, W[0], W[1], W[2], wTh,
                                            esrc, edst, deg, colv);

    // ---- layer 0 (K=128, HC=256, H=4)
    k_mgemm<128, 128><<<dim3(GB, 2), 256, 0, stream>>>(xf16, wTh, h_buf,
                                                       AS[0], AD[0], als, ald, 4, NN, 256);
    k_fagg4s<<<nsb, 256, 0, stream>>>(h_buf, als, ald, deg, colv,
                                      BI[0], GA[0], BE[0], MU[0], VA[0], xf16, NN);
    // ---- layer 1 (K=256, HC=256, H=4)
    k_mgemm<256, 128><<<dim3(GB, 2), 256, 0, stream>>>(xf16, wTh + 32768, h_buf,
                                                       AS[1], AD[1], als, ald, 4, NN, 256);
    k_fagg4s<<<nsb, 256, 0, stream>>>(h_buf, als, ald, deg, colv,
                                      BI[1], GA[1], BE[1], MU[1], VA[1], xf16, NN);
    // ---- layer 2 (K=256, HC=64, H=1)
    k_mgemm<256, 64><<<dim3(GB, 1), 256, 0, stream>>>(xf16, wTh + 98304, h_buf,
                                                      AS[2], AD[2], als, ald, 1, NN, 64);
    k_fagg1<<<nwb, 256, 0, stream>>>(h_buf, als, ald, deg, colv,
                                     BI[2], GA[2], BE[2], MU[2], VA[2], xpool, NN);

    // fused readout + MLP (512 threads: 8 node-subsets x 64 dims)
    k_poolfc<<<NGR, 512, 0, stream>>>(xpool, batch, fc1w, fc1b, fc2w, fc2b, fc3w, fc3b,
                                      (float*)d_out, NN);
    (void)in_sizes; (void)n_in; (void)out_size; (void)ws_size;
}

// Round 11
// 387.684 us; speedup vs baseline: 1.0270x; 1.0015x over previous
//
#include <hip/hip_runtime.h>
#include <hip/hip_fp16.h>

typedef unsigned short ushort_t;
typedef unsigned int uint_t;
typedef __attribute__((ext_vector_type(8))) _Float16 half8;
typedef __attribute__((ext_vector_type(4))) float f32x4;

#define NN 50000
#define NE 800000
#define NGR 256
#define MAXDEG 64   // max observed degree ~45 (+1 self-loop); Poisson(16) tail ~1e-18

// fill work split: 196 chunk-groups of 4096 edges; [0,FA_G) overlap prep,
// [FA_G,196) overlap GEMM-L0 (fagg0 is the first consumer of colv/deg).
#define FILL_GROUPS 196
#define FA_G 151

// async global->LDS, 16B per lane; LDS dest = wave-uniform base + lane*16
typedef __attribute__((address_space(3))) unsigned int as3_u32;
typedef const __attribute__((address_space(1))) unsigned int as1_u32c;
__device__ __forceinline__ void gld16(const ushort_t* g, void* lds_base) {
    __builtin_amdgcn_global_load_lds((as1_u32c*)g, (as3_u32*)lds_base, 16, 0, 0);
}

// ---- ELL fill body: one 4096-edge chunk-group slice per block ----
__device__ __forceinline__ void fill_body(int grp, int r,
                                          const int* __restrict__ esrc,
                                          const int* __restrict__ edst,
                                          int* __restrict__ deg,
                                          ushort_t* __restrict__ colv) {
    int base = grp * 4096 + (int)threadIdx.x * 4;
    int4 dv[4], sv[4];
    #pragma unroll
    for (int u = 0; u < 4; ++u) {
        int b = base + u * 1024;
        bool ok = b < NE;            // NE%4==0, b%4==0 -> b+3 < NE
        int bb = ok ? b : 0;
        dv[u] = *(const int4*)(edst + bb);
        sv[u] = *(const int4*)(esrc + bb);
        if (!ok) { dv[u].x = -1; dv[u].y = -1; dv[u].z = -1; dv[u].w = -1; }
    }
    const int lo = r * 6250;
    #pragma unroll
    for (int u = 0; u < 4; ++u) {
        const int* dp = (const int*)&dv[u];
        const int* sp = (const int*)&sv[u];
        #pragma unroll
        for (int j = 0; j < 4; ++j) {
            int d = dp[j];
            if ((unsigned)(d - lo) < 6250u) {
                int pos = atomicAdd(&deg[d], 1);           // 0-based edge slot
                if (pos < MAXDEG - 1) colv[(d << 6) + 1 + pos] = (ushort_t)sp[j];
            }
        }
    }
}

// ---- k_pf1: fill groups [0,FA_G) (first: long pole) + prep ----
// prep = x cast -> fp16, W -> transposed fp16, self-loop plant (slot 0,
// which the fill never writes -> disjoint; deg pre-zeroed by memset).
__global__ __launch_bounds__(256)
void k_pf1(const float* __restrict__ x0, __half* __restrict__ xf,
           const float* __restrict__ W0, const float* __restrict__ W1,
           const float* __restrict__ W2, __half* __restrict__ th,
           const int* __restrict__ esrc, const int* __restrict__ edst,
           int* __restrict__ deg, ushort_t* __restrict__ colv) {
    constexpr int FB1 = FA_G * 8;    // 1208
    if (blockIdx.x < FB1) {
        fill_body(blockIdx.x >> 3, blockIdx.x & 7, esrc, edst, deg, colv);
    } else {
        int i = (blockIdx.x - FB1) * 256 + threadIdx.x;
        if (i < 1600000) {
            float4 v = ((const float4*)x0)[i];
            __half2 a = __floats2half2_rn(v.x, v.y);
            __half2 b = __floats2half2_rn(v.z, v.w);
            *(__half2*)(xf + i * 4) = a;
            *(__half2*)(xf + i * 4 + 2) = b;
        } else if (i < 1600000 + 114688) {
            int w = i - 1600000;
            const float* W; int K, NC, idx, base;
            if (w < 32768)      { W = W0; K = 128; NC = 256; idx = w;         base = 0; }
            else if (w < 98304) { W = W1; K = 256; NC = 256; idx = w - 32768; base = 32768; }
            else                { W = W2; K = 256; NC = 64;  idx = w - 98304; base = 98304; }
            int k = idx / NC, n = idx % NC;
            th[base + n * K + k] = __float2half(W[idx]);
        } else if (i < 1600000 + 114688 + NN) {
            int n = i - 1714688;
            colv[n << 6] = (ushort_t)n;   // self-loop at slot 0
        }
    }
}

// ------- GEMM body (fp16 single-term) + fused attention-logit epilogue -------
template<int KD, int BN>
__device__ __forceinline__ void gemm_body(int bx, int by,
    const __half* __restrict__ Ax, const __half* __restrict__ Bth,
    __half* __restrict__ Hout, const float* __restrict__ a_s,
    const float* __restrict__ a_d, float* __restrict__ als,
    float* __restrict__ ald, int H, int M, int NC) {
    constexpr int BM = 128, BK = 32;
    __shared__ ushort_t sA[BM * BK];
    __shared__ ushort_t sB[BN * BK];
    const int tid = threadIdx.x;
    const int m0 = bx * BM;
    const int n0 = by * BN;
    const int wv = tid >> 6, ln = tid & 63;
    const int lrow = ln & 15, lq = ln >> 4;
    constexpr int RT = (BN == 128) ? 4 : 2;
    int wm, wn;
    if constexpr (BN == 128) { wm = (wv >> 1) * 64; wn = (wv & 1) * 64; }
    else                     { wm = wv * 32;        wn = 0; }
    const int roff = ln >> 2;
    const int coff = (ln & 3) * 8;

    f32x4 acc[RT][4] = {};

    for (int k0 = 0; k0 < KD; k0 += BK) {
        #pragma unroll
        for (int ch = 0; ch < 2; ++ch) {
            int rb = wv * 32 + ch * 16;
            size_t ga = (size_t)(m0 + rb + roff) * KD + k0 + coff;
            gld16((const ushort_t*)Ax + ga, &sA[rb * BK]);
        }
        if constexpr (BN == 128) {
            #pragma unroll
            for (int ch = 0; ch < 2; ++ch) {
                int rb = wv * 32 + ch * 16;
                size_t gb = (size_t)(n0 + rb + roff) * KD + k0 + coff;
                gld16((const ushort_t*)Bth + gb, &sB[rb * BK]);
            }
        } else {
            int rb = wv * 16;
            size_t gb = (size_t)(n0 + rb + roff) * KD + k0 + coff;
            gld16((const ushort_t*)Bth + gb, &sB[rb * BK]);
        }
        __syncthreads();
        half8 af[RT], bf[4];
        #pragma unroll
        for (int r = 0; r < RT; ++r)
            af[r] = *(const half8*)&sA[(wm + r * 16 + lrow) * BK + lq * 8];
        #pragma unroll
        for (int c = 0; c < 4; ++c)
            bf[c] = *(const half8*)&sB[(wn + c * 16 + lrow) * BK + lq * 8];
        #pragma unroll
        for (int r = 0; r < RT; ++r)
            #pragma unroll
            for (int c = 0; c < 4; ++c)
                acc[r][c] = __builtin_amdgcn_mfma_f32_16x16x32_f16(af[r], bf[c], acc[r][c], 0, 0, 0);
        __syncthreads();
    }
    // H-store (C/D layout: col=lane&15, row=(lane>>4)*4+reg)
    #pragma unroll
    for (int r = 0; r < RT; ++r) {
        #pragma unroll
        for (int c = 0; c < 4; ++c) {
            int colg = n0 + wn + c * 16 + lrow;
            #pragma unroll
            for (int j = 0; j < 4; ++j) {
                int row = m0 + wm + r * 16 + lq * 4 + j;
                if (row < M) Hout[(size_t)row * NC + colg] = __float2half(acc[r][c][j]);
            }
        }
    }
    // fused attention logits: this wave's 64 cols lie in exactly one head
    int hh = (n0 + wn) >> 6;
    float asv[4], adv[4];
    #pragma unroll
    for (int c = 0; c < 4; ++c) {
        int cg = (n0 + wn + c * 16 + lrow) & 63;
        asv[c] = a_s[hh * 64 + cg];
        adv[c] = a_d[hh * 64 + cg];
    }
    #pragma unroll
    for (int r = 0; r < RT; ++r) {
        #pragma unroll
        for (int j = 0; j < 4; ++j) {
            float ts = 0.f, td = 0.f;
            #pragma unroll
            for (int c = 0; c < 4; ++c) {
                float v = acc[r][c][j];
                ts += v * asv[c];
                td += v * adv[c];
            }
            #pragma unroll
            for (int m = 1; m < 16; m <<= 1) {
                ts += __shfl_xor(ts, m);
                td += __shfl_xor(td, m);
            }
            int row = m0 + wm + r * 16 + lq * 4 + j;
            if (lrow == 0 && row < M) {
                als[row * H + hh] = ts;
                ald[row * H + hh] = td;
            }
        }
    }
}

template<int KD, int BN>
__global__ __launch_bounds__(256)
void k_mgemm(const __half* __restrict__ Ax, const __half* __restrict__ Bth,
             __half* __restrict__ Hout,
             const float* __restrict__ a_s, const float* __restrict__ a_d,
             float* __restrict__ als, float* __restrict__ ald,
             int H, int M, int NC) {
    gemm_body<KD, BN>(blockIdx.x, blockIdx.y, Ax, Bth, Hout, a_s, a_d, als, ald, H, M, NC);
}

// ---- k_pf2: fill groups [FA_G,196) (first) + GEMM-L0 ----
// gemm reads only k_pf1's prep outputs (xf16, wTh); fill edges are the
// disjoint remainder. fagg0 (next launch) sees the completed colv/deg.
__global__ __launch_bounds__(256)
void k_pf2(const __half* __restrict__ Ax, const __half* __restrict__ Bth,
           __half* __restrict__ Hout,
           const float* __restrict__ a_s, const float* __restrict__ a_d,
           float* __restrict__ als, float* __restrict__ ald, int M,
           const int* __restrict__ esrc, const int* __restrict__ edst,
           int* __restrict__ deg, ushort_t* __restrict__ colv) {
    constexpr int FB2 = (FILL_GROUPS - FA_G) * 8;   // 360
    if (blockIdx.x < FB2) {
        fill_body(FA_G + (blockIdx.x >> 3), blockIdx.x & 7, esrc, edst, deg, colv);
    } else {
        int g = blockIdx.x - FB2;
        gemm_body<128, 128>(g >> 1, g & 1, Ax, Bth, Hout,
                            a_s, a_d, als, ald, 4, M, 256);
    }
}

// ---- CHANNEL-SPLIT fused softmax + aggregation + bias + BN + ELU (H=4) ----
// deg[] counts EDGES only (0-based); total slots = deg+1 (slot 0 = self).
__global__ __launch_bounds__(256)
void k_fagg4s(const __half* __restrict__ h, const float* __restrict__ als,
              const float* __restrict__ ald, const int* __restrict__ deg,
              const ushort_t* __restrict__ colv,
              const float* __restrict__ bias, const float* __restrict__ gam,
              const float* __restrict__ bet, const float* __restrict__ mu,
              const float* __restrict__ var,
              __half* __restrict__ xo, int M) {
    __shared__ uint_t wraw[4][64];     // uint per edge (2 fp16: this half's heads), 1KB
    int wv = threadIdx.x >> 6;
    int half = blockIdx.x & 1;
    int node = (blockIdx.x >> 1) * 4 + wv;
    if (node >= M) return;
    int l = threadIdx.x & 63;
    int dg = deg[node] + 1;            // [1,64] total slots incl. self-loop
    if (dg > MAXDEG) dg = MAXDEG;
    int rs = node << 6;

    // ---- phase A: logits -> e -> LDS weights + per-head denominator ----
    float2 ad = *(const float2*)(ald + (size_t)node * 4 + half * 2);
    bool vld = l < dg;
    int s = (int)colv[vld ? rs + l : rs];   // slot 0 (self-loop) always valid
    int cv = s;
    float2 av = *(const float2*)((const char*)als + ((size_t)(uint_t)s << 4) + half * 8);
    float e0 = av.x + ad.x; e0 = e0 > 0.f ? e0 : 0.2f * e0; e0 = vld ? __expf(e0) : 0.f;
    float e1 = av.y + ad.y; e1 = e1 > 0.f ? e1 : 0.2f * e1; e1 = vld ? __expf(e1) : 0.f;
    float d0 = e0, d1 = e1;
    __half2 p = __floats2half2_rn(e0, e1);
    wraw[wv][l] = *(uint_t*)&p;
    #pragma unroll
    for (int off = 1; off < 64; off <<= 1) {
        d0 += __shfl_xor(d0, off); d1 += __shfl_xor(d1, off);
    }

    // ---- phase B: weighted half-row gather (24-edge batches, LDS weights) ----
    float a0 = 0.f, a1 = 0.f;
    const uint_t shB = (uint_t)((l & 32) >> 1);        // head-in-half select: 0/16
    const uint_t loffB = (uint_t)(half * 256 + l * 4); // byte offset in row
    int nrem = dg;
    #pragma unroll
    for (int grp = 0; grp < 3; ++grp) {
        int g0 = grp * 24;
        if (g0 < nrem) {
            uint_t hu[3][8];
            #pragma unroll
            for (int bb = 0; bb < 3; ++bb) {
                if (g0 + bb * 8 < nrem) {
                    #pragma unroll
                    for (int u = 0; u < 8; ++u) {
                        int sv = __builtin_amdgcn_readlane(cv, g0 + bb * 8 + u);
                        const char* hp = (const char*)h + ((size_t)(uint_t)sv << 9);
                        hu[bb][u] = *(const uint_t*)(hp + loffB);
                    }
                }
            }
            #pragma unroll
            for (int bb = 0; bb < 3; ++bb) {
                if (g0 + bb * 8 < nrem) {
                    #pragma unroll
                    for (int u = 0; u < 8; ++u) {
                        int j = g0 + bb * 8 + u;           // static
                        uint_t w = wraw[wv][j];            // ds broadcast
                        uint_t afv = w >> shB;
                        asm("v_fma_mix_f32 %0, %1, %2, %0 op_sel:[0,0,0] op_sel_hi:[1,1,0]"
                            : "+v"(a0) : "v"(afv), "v"(hu[bb][u]));
                        asm("v_fma_mix_f32 %0, %1, %2, %0 op_sel:[0,1,0] op_sel_hi:[1,1,0]"
                            : "+v"(a1) : "v"(afv), "v"(hu[bb][u]));
                    }
                }
            }
        }
    }

    // ---- epilogue: 1/den + bias + BN + ELU (2 channels/lane) ----
    float den = (l & 32) ? d1 : d0;
    float inv = 1.f / (den + 1e-16f);
    int chg = half * 128 + l * 2;
    float2 bi = *(const float2*)(bias + chg);
    float2 ga = *(const float2*)(gam + chg);
    float2 be = *(const float2*)(bet + chg);
    float2 m2 = *(const float2*)(mu + chg);
    float2 v2 = *(const float2*)(var + chg);
    float o0 = a0 * inv + bi.x;
    float o1 = a1 * inv + bi.y;
    float bn0 = (o0 - m2.x) * rsqrtf(v2.x + 1e-5f) * ga.x + be.x;
    float bn1 = (o1 - m2.y) * rsqrtf(v2.y + 1e-5f) * ga.y + be.y;
    float f0 = bn0 > 0.f ? bn0 : (__expf(bn0) - 1.f);
    float f1 = bn1 > 0.f ? bn1 : (__expf(bn1) - 1.f);
    __half2 pk = __floats2half2_rn(f0, f1);
    *(uint_t*)&xo[(size_t)node * 256 + chg] = *(uint_t*)&pk;
}

// ---- FUSED softmax + aggregation + bias + BN + ELU (H=1, ELL) ----
__global__ __launch_bounds__(256)
void k_fagg1(const __half* __restrict__ h, const float* __restrict__ als,
             const float* __restrict__ ald, const int* __restrict__ deg,
             const ushort_t* __restrict__ colv,
             const float* __restrict__ bias, const float* __restrict__ gam,
             const float* __restrict__ bet, const float* __restrict__ mu,
             const float* __restrict__ var,
             float* __restrict__ xf, int M) {
    __shared__ uint_t wraw[4][64];
    int node = blockIdx.x * 4 + (threadIdx.x >> 6);
    if (node >= M) return;
    int wv = (threadIdx.x >> 6) & 3;
    int l = threadIdx.x & 63;
    int dg = deg[node] + 1;
    if (dg > MAXDEG) dg = MAXDEG;
    int rs = node << 6;

    float ad = ald[node];
    bool vld = l < dg;
    int s = (int)colv[vld ? rs + l : rs];
    int cv = s;
    float e = als[s] + ad; e = e > 0.f ? e : 0.2f * e; e = vld ? __expf(e) : 0.f;
    float d0 = e;
    wraw[wv][l] = __float_as_uint(e);
    #pragma unroll
    for (int off = 1; off < 64; off <<= 1) d0 += __shfl_xor(d0, off);

    float a0 = 0.f;
    int nrem = dg;
    #pragma unroll
    for (int grp = 0; grp < 3; ++grp) {
        int g0 = grp * 24;
        if (g0 < nrem) {
            uint_t hu[3][8];
            #pragma unroll
            for (int bb = 0; bb < 3; ++bb) {
                if (g0 + bb * 8 < nrem) {
                    #pragma unroll
                    for (int u = 0; u < 8; ++u) {
                        int sv = __builtin_amdgcn_readlane(cv, g0 + bb * 8 + u);
                        const ushort_t* hp = (const ushort_t*)h + ((size_t)(uint_t)sv << 6);
                        hu[bb][u] = (uint_t)hp[l];
                    }
                }
            }
            #pragma unroll
            for (int bb = 0; bb < 3; ++bb) {
                if (g0 + bb * 8 < nrem) {
                    #pragma unroll
                    for (int u = 0; u < 8; ++u) {
                        int j = g0 + bb * 8 + u;
                        uint_t wfv = wraw[wv][j];
                        asm("v_fma_mix_f32 %0, %1, %2, %0 op_sel:[0,0,0] op_sel_hi:[0,1,0]"
                            : "+v"(a0) : "v"(wfv), "v"(hu[bb][u]));
                    }
                }
            }
        }
    }

    float inv = 1.f / (d0 + 1e-16f);
    float o = a0 * inv + bias[l];
    float bn = (o - mu[l]) * rsqrtf(var[l] + 1e-5f) * gam[l] + bet[l];
    float fo = bn > 0.f ? bn : (__expf(bn) - 1.f);
    xf[(size_t)node * 64 + l] = fo;
}

// ---- fused pooling + MLP: 512 threads = 8 node-subsets x 64 dims, LDS reduce ----
__global__ __launch_bounds__(512)
void k_poolfc(const float* __restrict__ x, const int* __restrict__ batch,
              const float* __restrict__ fc1w, const float* __restrict__ fc1b,
              const float* __restrict__ fc2w, const float* __restrict__ fc2b,
              const float* __restrict__ fc3w, const float* __restrict__ fc3b,
              float* __restrict__ out, int M) {
    __shared__ float ssum[8][64];
    __shared__ float smax[8][64];
    __shared__ float hb[192];
    __shared__ float h1[64];
    __shared__ float h2[32];
    int g = blockIdx.x, t = threadIdx.x;
    int d = t & 63, sub = t >> 6;    // 8 subsets
    int lo = 0, hi = M;
    while (lo < hi) { int mid = (lo + hi) >> 1; if (batch[mid] < g) lo = mid + 1; else hi = mid; }
    int s = lo;
    lo = 0; hi = M;
    while (lo < hi) { int mid = (lo + hi) >> 1; if (batch[mid] < g + 1) lo = mid + 1; else hi = mid; }
    int e = lo;
    float sum = 0.f, mx = -3.0e38f;
    for (int n = s + sub; n < e; n += 8) {
        float v = x[(size_t)n * 64 + d];
        sum += v; mx = fmaxf(mx, v);
    }
    ssum[sub][d] = sum; smax[sub][d] = mx;
    __syncthreads();
    if (t < 64) {
        float sm = 0.f, m2 = -3.0e38f;
        #pragma unroll
        for (int k = 0; k < 8; ++k) { sm += ssum[k][t]; m2 = fmaxf(m2, smax[k][t]); }
        int cnt = e - s;
        hb[t] = sm / (float)(cnt > 1 ? cnt : 1);
        hb[64 + t] = (cnt == 0) ? 0.f : m2;
        hb[128 + t] = sm;
    }
    __syncthreads();
    if (t < 64) {
        float s1 = fc1b[t];
        for (int k = 0; k < 192; ++k) s1 += hb[k] * fc1w[k * 64 + t];
        h1[t] = fmaxf(s1, 0.f);
    }
    __syncthreads();
    if (t < 32) {
        float s2 = fc2b[t];
        for (int k = 0; k < 64; ++k) s2 += h1[k] * fc2w[k * 32 + t];
        h2[t] = fmaxf(s2, 0.f);
    }
    __syncthreads();
    if (t == 0) {
        float s3 = fc3b[0];
        for (int k = 0; k < 32; ++k) s3 += h2[k] * fc3w[k];
        out[g] = s3;
    }
}

extern "C" void kernel_launch(void* const* d_in, const int* in_sizes, int n_in,
                              void* d_out, int out_size, void* d_ws, size_t ws_size,
                              hipStream_t stream) {
    const float* x0     = (const float*)d_in[0];
    const int* ei       = (const int*)d_in[1];
    const int* batch    = (const int*)d_in[2];
    const float* W[3]   = {(const float*)d_in[3],  (const float*)d_in[11], (const float*)d_in[19]};
    const float* AS[3]  = {(const float*)d_in[4],  (const float*)d_in[12], (const float*)d_in[20]};
    const float* AD[3]  = {(const float*)d_in[5],  (const float*)d_in[13], (const float*)d_in[21]};
    const float* BI[3]  = {(const float*)d_in[6],  (const float*)d_in[14], (const float*)d_in[22]};
    const float* GA[3]  = {(const float*)d_in[7],  (const float*)d_in[15], (const float*)d_in[23]};
    const float* BE[3]  = {(const float*)d_in[8],  (const float*)d_in[16], (const float*)d_in[24]};
    const float* MU[3]  = {(const float*)d_in[9],  (const float*)d_in[17], (const float*)d_in[25]};
    const float* VA[3]  = {(const float*)d_in[10], (const float*)d_in[18], (const float*)d_in[26]};
    const float* fc1w = (const float*)d_in[27];
    const float* fc1b = (const float*)d_in[28];
    const float* fc2w = (const float*)d_in[29];
    const float* fc2b = (const float*)d_in[30];
    const float* fc3w = (const float*)d_in[31];
    const float* fc3b = (const float*)d_in[32];

    // ELL(ushort) workspace: top of use = 72,454,144 B (< 108,953,600 B proven safe).
    char* ws = (char*)d_ws;
    ushort_t* colv = (ushort_t*)(ws);                  // 6,400,000 B (50k x 64 ELL, u16)
    int*   deg    = (int*)  (ws + 6400000);            // 200,000 B
    float* als    = (float*)(ws + 6600192);            // 800,000 B
    float* ald    = (float*)(ws + 7400192);            // 800,000 B
    __half* wTh   = (__half*)(ws + 8200192);           // 229,376 B (3 layers packed)
    __half* h_buf = (__half*)(ws + 8429568);           // 25,600,000 B
    __half* xf16  = (__half*)(ws + 34029568);          // 25,624,576 B (50048 rows x 256)
    float* xpool  = (float*)(ws + 59654144);           // 12,800,000 B -> 72,454,144 B

    const int* esrc = ei;
    const int* edst = ei + NE;

    const int GB = (NN + 127) / 128; // 391
    const int FB1 = FA_G * 8;                       // 1208 fill blocks in k_pf1
    const int FB2 = (FILL_GROUPS - FA_G) * 8;       // 360 fill blocks in k_pf2
    const int PREPB = (1600000 + 114688 + NN + 255) / 256; // 6894
    int nwb = (NN + 3) / 4;          // 12500
    int nsb = nwb * 2;               // 25000 (channel-split: x2 halves)

    // deg = 0 (edge count; self-loop handled by slot-0 plant in prep blocks)
    hipMemsetAsync(deg, 0, NN * sizeof(int), stream);

    // ---- stage 1: fill[0,151) (long pole, first) overlapped with prep
    k_pf1<<<FB1 + PREPB, 256, 0, stream>>>(x0, xf16, W[0], W[1], W[2], wTh,
                                           esrc, edst, deg, colv);
    // ---- stage 2: fill[151,196) (first) overlapped with GEMM-L0
    k_pf2<<<FB2 + 782, 256, 0, stream>>>(xf16, wTh, h_buf, AS[0], AD[0], als, ald, NN,
                                         esrc, edst, deg, colv);

    // ---- layer 0 aggregation
    k_fagg4s<<<nsb, 256, 0, stream>>>(h_buf, als, ald, deg, colv,
                                      BI[0], GA[0], BE[0], MU[0], VA[0], xf16, NN);
    // ---- layer 1 (K=256, HC=256, H=4)
    k_mgemm<256, 128><<<dim3(GB, 2), 256, 0, stream>>>(xf16, wTh + 32768, h_buf,
                                                       AS[1], AD[1], als, ald, 4, NN, 256);
    k_fagg4s<<<nsb, 256, 0, stream>>>(h_buf, als, ald, deg, colv,
                                      BI[1], GA[1], BE[1], MU[1], VA[1], xf16, NN);
    // ---- layer 2 (K=256, HC=64, H=1)
    k_mgemm<256, 64><<<dim3(GB, 1), 256, 0, stream>>>(xf16, wTh + 98304, h_buf,
                                                      AS[2], AD[2], als, ald, 1, NN, 64);
    k_fagg1<<<nwb, 256, 0, stream>>>(h_buf, als, ald, deg, colv,
                                     BI[2], GA[2], BE[2], MU[2], VA[2], xpool, NN);

    // fused readout + MLP (512 threads: 8 node-subsets x 64 dims)
    k_poolfc<<<NGR, 512, 0, stream>>>(xpool, batch, fc1w, fc1b, fc2w, fc2b, fc3w, fc3b,
                                      (float*)d_out, NN);
    (void)in_sizes; (void)n_in; (void)out_size; (void)ws_size;
}